// Round 22
// baseline (34.942 us; speedup 1.0000x reference)
//
#include <hip/hip_runtime.h>

#define DTF (1.0f/120.0f)

constexpr int Bn = 2048, Tn = 2048, NS = Tn - 1, ZF = Tn * 3;
constexpr int BT = 128;               // 2 waves
constexpr int NHEAD = 16;             // head blocks (lane = trajectory, steps [0,96))
constexpr int NBLK = NHEAD + Bn;      // 2064 blocks; head first (overlap)
constexpr int GRAN = ZF / 4;          // 1536 16B-granules per trajectory
constexpr int WS_PART = 4096;         // part[] offset in ws (cv at 0)

// padded LDS: granule g -> byte offset (16B-aligned, +16B per 32 granules)
__device__ __forceinline__ int offb(int g) { return (g + (g >> 5)) << 4; }

// ---- gains: 48-iter 2x2 Riccati -> 7 converged floats ----
__global__ void gains_kernel(const float* __restrict__ params, float* __restrict__ cv)
{
    if (threadIdx.x != 0) return;
    const float dt = DTF, damping = params[1];
    const float a = 1.f - dt * damping;
    const float dt2 = dt * dt, a2 = a * a;
    const float qp = 2e-10f, qv = 3e-7f, qth = 1e-2f, qdth = 1e-1f;
    const float Rp = 2.5e-7f, Rt = 9.1e-3f;
    float x00 = 0.01f, x01 = 0.f, x11 = 0.01f, t00 = 0.01f, t01 = 0.f, t11 = 0.01f;
    float kx0, kx1, kt0, kt1, isx, ist, det;
    for (int t = 0; t < 48; ++t) {
        float Pp00 = fmaf(dt2, x11, fmaf(2.f * dt, x01, x00)) + qp;
        float Pp01 = a * fmaf(dt, x11, x01);
        float Pp11 = fmaf(a2, x11, qv);
        float Sx = Pp00 + Rp; isx = __builtin_amdgcn_rcpf(Sx);
        kx0 = Pp00 * isx; kx1 = Pp01 * isx;
        x00 = Pp00 - kx0 * Pp00; x01 = Pp01 - kx0 * Pp01; x11 = Pp11 - kx1 * Pp01;
        float Tp00 = fmaf(dt2, t11, fmaf(2.f * dt, t01, t00)) + qth;
        float Tp01 = fmaf(dt, t11, t01);
        float Tp11 = t11 + qdth;
        float St = Tp00 + Rt; ist = __builtin_amdgcn_rcpf(St);
        kt0 = Tp00 * ist; kt1 = Tp01 * ist;
        t00 = Tp00 - kt0 * Tp00; t01 = Tp01 - kt0 * Tp01; t11 = Tp11 - kt1 * Tp01;
        det = Sx * Sx * St;
    }
    cv[0] = kx0; cv[1] = kx1; cv[2] = kt0; cv[3] = kt1;
    cv[4] = isx; cv[5] = ist; cv[6] = det;
}

// ---- main: streamed trajectory/block, chunk-per-lane L=16 W=80; head in 16 blocks ----
__global__ __launch_bounds__(BT, 3) void ekf_main(const float* __restrict__ params,
                                                  const float* __restrict__ meas,
                                                  const float* __restrict__ cv,
                                                  double* __restrict__ part)
{
    __shared__ __align__(16) float lds[GRAN * 4 + 192];   // 25.3 KB padded
    __shared__ double wsum[2];

    const int tid = threadIdx.x;
    const int B = blockIdx.x;
    const float dt = DTF, fric = params[0], damping = params[1];
    const float a = 1.f - dt * damping, dfr = dt * fric;
    char* __restrict__ ldsc = (char*)lds;
    float facc = 0.f;

    if (B >= NHEAD) {
        // ---------------- main block: trajectory Bm, amp-1.0 streaming ----------------
        const int Bm = B - NHEAD;
        const float* __restrict__ zbf = meas + (size_t)Bm * ZF;

        float4 st[12];
        #pragma unroll
        for (int i = 0; i < 12; ++i)                      // lane-linear full-line loads
            st[i] = *(const float4*)(zbf + 4 * (128 * i + tid));
        const float ckx0 = cv[0], ckx1 = cv[1], ckt0 = cv[2], ckt1 = cv[3];
        const float cisx = cv[4], cist = cv[5], cdet = cv[6];
        #pragma unroll
        for (int i = 0; i < 12; ++i)                      // padded LDS writes (~2-way)
            *(float4*)(ldsc + offb(128 * i + tid)) = st[i];
        __syncthreads();

        // lane = chunk c: owns [16c, 16c+16), warm-up 80; c<=5 owned by head blocks
        const int c = tid;
        const int jw = (c <= 5) ? 0 : (16 * c - 80);
        const int gB = (3 * jw) >> 2;                     // 12c-60 (c>=6), 16B-aligned
        const int ro1v = (c <= 5) ? 0 : (min(16 * c + 16, NS) - jw);

        float4 u0 = *(const float4*)(ldsc + offb(gB));
        float4 u1 = *(const float4*)(ldsc + offb(gB + 1));
        float s0 = u0.x, s1 = u0.y, s4 = u0.z;
        float s2 = (u0.w - u0.x) / dt, s3 = (u1.x - u0.y) / dt, s5 = (u1.y - u0.z) / dt;
        float accP = 0.f, accT = 0.f;

#define ZREADM(M, CL) \
    float4 v0 = *(const float4*)(ldsc + offb(min(gB + 3*(M),     (CL)))); \
    float4 v1 = *(const float4*)(ldsc + offb(min(gB + 3*(M) + 1, (CL)))); \
    float4 v2 = *(const float4*)(ldsc + offb(min(gB + 3*(M) + 2, (CL)))); \
    float4 v3 = *(const float4*)(ldsc + offb(min(gB + 3*(M) + 3, (CL)))); \
    float zv[12] = { v0.w, v1.x, v1.y, v1.z, v1.w, v2.x, \
                     v2.y, v2.z, v2.w, v3.x, v3.y, v3.z };

#define WSTEP(SS) { \
    float p0 = fmaf(dt, s2, s0), p1 = fmaf(dt, s3, s1), p4 = fmaf(dt, s5, s4); \
    float p2 = fmaf(a, s2, -copysignf(dfr, s2)); \
    float p3 = fmaf(a, s3, -copysignf(dfr, s3)); \
    float y0 = zv[3*(SS)] - p0, y1 = zv[3*(SS)+1] - p1, y2 = zv[3*(SS)+2] - p4; \
    s0 = fmaf(ckx0, y0, p0); s1 = fmaf(ckx0, y1, p1); \
    s2 = fmaf(ckx1, y0, p2); s3 = fmaf(ckx1, y1, p3); \
    s4 = fmaf(ckt0, y2, p4); s5 = fmaf(ckt1, y2, s5); }

#define OSTEP(M, SS) { \
    float p0 = fmaf(dt, s2, s0), p1 = fmaf(dt, s3, s1), p4 = fmaf(dt, s5, s4); \
    float p2 = fmaf(a, s2, -copysignf(dfr, s2)); \
    float p3 = fmaf(a, s3, -copysignf(dfr, s3)); \
    float y0 = zv[3*(SS)] - p0, y1 = zv[3*(SS)+1] - p1, y2 = zv[3*(SS)+2] - p4; \
    s0 = fmaf(ckx0, y0, p0); s1 = fmaf(ckx0, y1, p1); \
    s2 = fmaf(ckx1, y0, p2); s3 = fmaf(ckx1, y1, p3); \
    s4 = fmaf(ckt0, y2, p4); s5 = fmaf(ckt1, y2, s5); \
    if (4*(M) + (SS) < ro1v) { \
        accP = fmaf(y0, y0, fmaf(y1, y1, accP)); \
        accT = fmaf(y2, y2, accT); } }

        #pragma unroll 4
        for (int m = 0; m < 20; ++m) {                    // warm: no accumulation
            ZREADM(m, GRAN - 1)
            WSTEP(0) WSTEP(1) WSTEP(2) WSTEP(3)
        }
        #pragma unroll
        for (int m = 20; m < 24; ++m) {                   // owned: steps 80..95
            ZREADM(m, GRAN - 1)
            OSTEP(m, 0) OSTEP(m, 1) OSTEP(m, 2) OSTEP(m, 3)
        }
#undef OSTEP
#undef WSTEP
#undef ZREADM
        int nown = max(ro1v - 80, 0);
        facc = (float)nown * cdet + cisx * accP + cist * accT;
    } else {
        // ---------------- head block: lane = trajectory, exact steps [0,96) ----------
        const int t = B * BT + tid;
        const float* __restrict__ zp = meas + (size_t)t * ZF;
        const float dt2 = dt * dt, a2 = a * a;
        const float qp = 2e-10f, qv = 3e-7f, qth = 1e-2f, qdth = 1e-1f;
        const float Rp = 2.5e-7f, Rt = 9.1e-3f;

        float4 n0 = *(const float4*)(zp + 0), n1 = *(const float4*)(zp + 4);
        float4 n2 = *(const float4*)(zp + 8), n3 = *(const float4*)(zp + 12);
        float s0 = n0.x, s1 = n0.y, s4 = n0.z;
        float s2 = (n0.w - n0.x) / dt, s3 = (n1.x - n0.y) / dt, s5 = (n1.y - n0.z) / dt;
        float hx00 = 0.01f, hx01 = 0.f, hx11 = 0.01f;
        float ht00 = 0.01f, ht01 = 0.f, ht11 = 0.01f;

        #pragma unroll 2
        for (int m = 0; m < 24; ++m) {
            float4 c0 = n0, c1 = n1, c2 = n2, c3 = n3;
            if (m < 23) {                                  // prefetch next batch
                n0 = *(const float4*)(zp + 4 * (3*m + 3));
                n1 = *(const float4*)(zp + 4 * (3*m + 4));
                n2 = *(const float4*)(zp + 4 * (3*m + 5));
                n3 = *(const float4*)(zp + 4 * (3*m + 6));
            }
            float zv[12] = { c0.w, c1.x, c1.y, c1.z, c1.w, c2.x,
                             c2.y, c2.z, c2.w, c3.x, c3.y, c3.z };
            #pragma unroll
            for (int ss = 0; ss < 4; ++ss) {
                float Pp00 = fmaf(dt2, hx11, fmaf(2.f*dt, hx01, hx00)) + qp;
                float Pp01 = a * fmaf(dt, hx11, hx01);
                float Pp11 = fmaf(a2, hx11, qv);
                float Sx = Pp00 + Rp, isx = __builtin_amdgcn_rcpf(Sx);
                float kx0 = Pp00 * isx, kx1 = Pp01 * isx;
                hx00 = Pp00 - kx0*Pp00; hx01 = Pp01 - kx0*Pp01; hx11 = Pp11 - kx1*Pp01;
                float Tp00 = fmaf(dt2, ht11, fmaf(2.f*dt, ht01, ht00)) + qth;
                float Tp01 = fmaf(dt, ht11, ht01);
                float Tp11 = ht11 + qdth;
                float St = Tp00 + Rt, ist = __builtin_amdgcn_rcpf(St);
                float kt0 = Tp00 * ist, kt1 = Tp01 * ist;
                ht00 = Tp00 - kt0*Tp00; ht01 = Tp01 - kt0*Tp01; ht11 = Tp11 - kt1*Tp01;
                float p0 = fmaf(dt, s2, s0), p1 = fmaf(dt, s3, s1), p4 = fmaf(dt, s5, s4);
                float p2 = fmaf(a, s2, -copysignf(dfr, s2));
                float p3 = fmaf(a, s3, -copysignf(dfr, s3));
                float y0 = zv[3*ss] - p0, y1 = zv[3*ss+1] - p1, y2 = zv[3*ss+2] - p4;
                s0 = fmaf(kx0, y0, p0); s1 = fmaf(kx0, y1, p1);
                s2 = fmaf(kx1, y0, p2); s3 = fmaf(kx1, y1, p3);
                s4 = fmaf(kt0, y2, p4); s5 = fmaf(kt1, y2, s5);
                facc += Sx*Sx*St + isx * fmaf(y0, y0, y1*y1) + ist * y2*y2;
            }
        }
    }

    // per-wave reduce -> block partial (no atomics)
    double acc = (double)facc;
    for (int off = 32; off; off >>= 1) acc += __shfl_down(acc, off);
    if ((tid & 63) == 0) wsum[tid >> 6] = acc;
    __syncthreads();
    if (tid == 0) part[B] = wsum[0] + wsum[1];
}

// ---- finalize: reduce 2064 partials ----
__global__ void finalize_kernel(const double* __restrict__ part, float* __restrict__ out)
{
    const int tid = threadIdx.x;               // 1024 threads
    double v = part[tid] + part[tid + 1024];
    if (tid < NBLK - 2048) v += part[2048 + tid];
    for (int off = 32; off; off >>= 1) v += __shfl_down(v, off);
    __shared__ double wp[16];
    if ((tid & 63) == 0) wp[tid >> 6] = v;
    __syncthreads();
    if (tid == 0) {
        double t = 0.0;
        #pragma unroll
        for (int i = 0; i < 16; ++i) t += wp[i];
        out[0] = (float)(t / ((double)Bn * (double)NS));
    }
}

extern "C" void kernel_launch(void* const* d_in, const int* in_sizes, int n_in,
                              void* d_out, int out_size, void* d_ws, size_t ws_size,
                              hipStream_t stream)
{
    const float* params = (const float*)d_in[0];
    const float* meas = (const float*)d_in[1];
    float* cvp = (float*)d_ws;
    double* part = (double*)((char*)d_ws + WS_PART);
    float* out = (float*)d_out;

    hipLaunchKernelGGL(gains_kernel, dim3(1), dim3(64), 0, stream, params, cvp);
    hipLaunchKernelGGL(ekf_main, dim3(NBLK), dim3(BT), 0, stream, params, meas, cvp, part);
    hipLaunchKernelGGL(finalize_kernel, dim3(1), dim3(1024), 0, stream, part, out);
}